// Round 5
// baseline (102.281 us; speedup 1.0000x reference)
//
#include <hip/hip_runtime.h>
#include <cstdint>

#define NCLS 13
#define SMAX 10
#define PTHRESH 0.05f
#define FPS_SEG 16       // blocks per (b,c)
#define FPS_T 512        // threads per FPS block (8 waves)
#define FPS_PPT 8        // points per thread: 16*512*8 = 65536 (state fits registers)
#define NSLOT 128        // publisher waves per (b,c) = FPS_SEG * FPS_T/64
#define GABLK 256        // k_setup blocks per batch (N/256)
#define BB 2             // batch
#define SLOT_DWORDS (BB * NCLS * SMAX * NSLOT * 2)

// Exact (un-fused) squared distance, matching numpy's ((dx*dx + dy*dy) + dz*dz) in f32.
__device__ __forceinline__ float d2f(float ax, float ay, float az,
                                     float bx, float by, float bz) {
    float dx = ax - bx;
    float dy = ay - by;
    float dz = az - bz;
    return __fadd_rn(__fadd_rn(__fmul_rn(dx, dx), __fmul_rn(dy, dy)), __fmul_rn(dz, dz));
}

// Monotone mapping float -> uint32. Never 0 for non-NaN input => key==0 means "empty".
__device__ __forceinline__ unsigned int fmono(float f) {
    unsigned int u = __float_as_uint(f);
    return (u & 0x80000000u) ? ~u : (u | 0x80000000u);
}

// Kernel A: class softmax, shifted coords (SoA), PER-BLOCK partial counts/first-index
// (full overwrite -> no zero-init, no global atomics), plus zeroing the FPS slots.
__global__ void k_setup(const float* __restrict__ logits, const float* __restrict__ pts,
                        const float* __restrict__ offs, float* __restrict__ probs,
                        float* __restrict__ sx, float* __restrict__ sy, float* __restrict__ sz,
                        unsigned int* __restrict__ pcnt, unsigned int* __restrict__ pfst,
                        unsigned int* __restrict__ slots32, int N) {
    int b = blockIdx.y;
    int n = blockIdx.x * blockDim.x + threadIdx.x;
    int t = threadIdx.x;
    __shared__ unsigned int sC[NCLS], sF[NCLS];
    if (t < NCLS) { sC[t] = 0u; sF[t] = 0xFFFFFFFFu; }
    __syncthreads();

    // zero FPS slots (every call: graph replays leave stale nonzero keys behind)
    if (b == 0) {
        for (unsigned int i = blockIdx.x * blockDim.x + t; i < SLOT_DWORDS;
             i += GABLK * 256)
            slots32[i] = 0u;
    }

    if (n < N) {
        size_t bn = (size_t)b * N + n;
        const float* L = logits + bn * NCLS;
        float v[NCLS];
        float mx = -INFINITY;
#pragma unroll
        for (int c = 0; c < NCLS; ++c) { v[c] = L[c]; mx = fmaxf(mx, v[c]); }
        float s = 0.f;
#pragma unroll
        for (int c = 0; c < NCLS; ++c) { v[c] = expf(v[c] - mx); s += v[c]; }
        int lane = t & 63;
        int wave_base = n - lane;
#pragma unroll
        for (int c = 0; c < NCLS; ++c) {
            float p = v[c] / s;
            probs[((size_t)b * NCLS + c) * N + n] = p;
            unsigned long long m = __ballot(p > PTHRESH);
            if (lane == 0 && m) {
                atomicAdd(&sC[c], (unsigned int)__popcll(m));
                atomicMin(&sF[c], (unsigned int)(wave_base + __ffsll(m) - 1));
            }
        }
        float x = pts[bn * 3 + 0] + offs[bn * 3 + 0];
        float y = pts[bn * 3 + 1] + offs[bn * 3 + 1];
        float z = pts[bn * 3 + 2] + offs[bn * 3 + 2];
        sx[bn] = x; sy[bn] = y; sz[bn] = z;
    }
    __syncthreads();
    if (t < NCLS) {
        pcnt[(b * NCLS + t) * GABLK + blockIdx.x] = sC[t];
        pfst[(b * NCLS + t) * GABLK + blockIdx.x] = sF[t];
    }
}

// Kernel B: deterministic FPS, wave-autonomous. 16 blocks x 8 waves per (b,c) = 128
// publisher waves; slots per (bc,step) = 128 u64 (each polling lane owns 2 slots).
// Per step: thread partial argmax -> 64-lane butterfly -> lane0 relaxed-store own slot
// -> every lane relaxed-polls its 2 slots (no buffer_inv) -> butterfly max = winner.
// No __syncthreads, no LDS, no fences: the u64 key is pure value communication.
__global__ __launch_bounds__(FPS_T) void k_fps(
    const float* __restrict__ probs,
    const float* __restrict__ sx, const float* __restrict__ sy, const float* __restrict__ sz,
    const unsigned int* __restrict__ pcnt, const unsigned int* __restrict__ pfst,
    int* __restrict__ nseeds, float* __restrict__ seedxyz,
    unsigned long long* __restrict__ slots, int N) {
    int g = blockIdx.x;
    int c = blockIdx.y;
    int b = blockIdx.z;
    int bc = b * NCLS + c;
    int t = threadIdx.x, lane = t & 63, w = t >> 6;

    // Reduce per-block partials (each wave redundantly; identical ops -> identical result)
    const unsigned int* pc = pcnt + (size_t)bc * GABLK;
    const unsigned int* pf = pfst + (size_t)bc * GABLK;
    uint4 c4 = *(const uint4*)(pc + lane * 4);
    uint4 f4 = *(const uint4*)(pf + lane * 4);
    unsigned int cnt = c4.x + c4.y + c4.z + c4.w;
    unsigned int fst = min(min(f4.x, f4.y), min(f4.z, f4.w));
#pragma unroll
    for (int off = 1; off < 64; off <<= 1) {
        cnt += __shfl_xor(cnt, off, 64);
        fst = min(fst, __shfl_xor(fst, off, 64));
    }
    int ns = min(SMAX, min((int)cnt / 50, (int)cnt));
    if (g == 0 && t == 0) nseeds[bc] = ns;
    if (ns == 0) return;

    const float* px = sx + (size_t)b * N;
    const float* py = sy + (size_t)b * N;
    const float* pz = sz + (size_t)b * N;
    const float* pp = probs + (size_t)bc * N;

    int base = g * (FPS_T * FPS_PPT) + t;
    float X[FPS_PPT], Y[FPS_PPT], Z[FPS_PPT], m[FPS_PPT];
    unsigned int vm = 0;
#pragma unroll
    for (int j = 0; j < FPS_PPT; ++j) {
        int n = base + (j << 9);
        X[j] = px[n]; Y[j] = py[n]; Z[j] = pz[n];
        if (pp[n] > PTHRESH) vm |= (1u << j);
        m[j] = INFINITY;
    }

    int st = (int)fst;
    float cx = px[st], cy = py[st], cz = pz[st];
    if (g == 0 && t == 0) {
        float* sd = seedxyz + (size_t)bc * SMAX * 3;
        sd[0] = cx; sd[1] = cy; sd[2] = cz;
    }

    for (int s = 1; s < ns; ++s) {
        float best = -INFINITY;
        int bidx = 0;
#pragma unroll
        for (int j = 0; j < FPS_PPT; ++j) {   // ascending n => first-occurrence tiebreak
            int n = base + (j << 9);
            float d2 = d2f(X[j], Y[j], Z[j], cx, cy, cz);
            float add = ((vm >> j) & 1u) ? 0.0f : -INFINITY;
            float nm = fminf(m[j], __fadd_rn(d2, add));
            m[j] = nm;
            if (nm > best) { best = nm; bidx = n; }
        }
        unsigned long long key =
            ((unsigned long long)fmono(best) << 32) | (unsigned int)(~(unsigned int)bidx);
#pragma unroll
        for (int off = 1; off < 64; off <<= 1) {
            unsigned long long ok = __shfl_xor(key, off, 64);
            if (ok > key) key = ok;
        }
        unsigned long long* sl = slots + ((size_t)bc * SMAX + s) * NSLOT;
        if (lane == 0)
            __hip_atomic_store(&sl[g * (FPS_T / 64) + w], key,
                               __ATOMIC_RELAXED, __HIP_MEMORY_SCOPE_AGENT);
        asm volatile("" ::: "memory");   // pin publish before poll (no runtime cost)
        unsigned long long k1 = 0ULL, k2 = 0ULL;
        while (true) {
            if (k1 == 0ULL)
                k1 = __hip_atomic_load(&sl[lane], __ATOMIC_RELAXED, __HIP_MEMORY_SCOPE_AGENT);
            if (k2 == 0ULL)
                k2 = __hip_atomic_load(&sl[64 + lane], __ATOMIC_RELAXED,
                                       __HIP_MEMORY_SCOPE_AGENT);
            if (__all((k1 != 0ULL) && (k2 != 0ULL))) break;
        }
        asm volatile("" ::: "memory");
        unsigned long long k = (k1 > k2) ? k1 : k2;
#pragma unroll
        for (int off = 1; off < 64; off <<= 1) {
            unsigned long long ok = __shfl_xor(k, off, 64);
            if (ok > k) k = ok;
        }
        int widx = (int)(~(unsigned int)k);
        cx = px[widx]; cy = py[widx]; cz = pz[widx];
        if (g == 0 && t == 0) {
            float* sd = seedxyz + ((size_t)bc * SMAX + s) * 3;
            sd[0] = cx; sd[1] = cy; sd[2] = cz;
        }
    }
}

// Kernel C: 512-thread block owns 64 points. Wave w (lane=point) handles classes
// {w, w+8} in pass 1 (gd + partial sumexp -> LDS), rows k==w (mod 8) in pass 2.
// 8x the waves of the per-point version -> occupancy-capped instead of latency-bound.
__global__ __launch_bounds__(512) void k_out(
    const float* __restrict__ probs,
    const float* __restrict__ sx, const float* __restrict__ sy,
    const float* __restrict__ sz,
    const int* __restrict__ nseeds, const float* __restrict__ seedxyz,
    float* __restrict__ out, int N) {
    int b = blockIdx.y;
    int t = threadIdx.x;
    int lane = t & 63;       // point within 64-point tile
    int wv = t >> 6;         // wave 0..7
    int n = blockIdx.x * 64 + lane;

    __shared__ float S[NCLS * SMAX * 3];
    __shared__ int NSs[NCLS];
    __shared__ float gdS[NCLS][64];
    __shared__ float psum[8][64];
    if (t < NCLS * SMAX * 3) S[t] = seedxyz[(size_t)b * NCLS * SMAX * 3 + t];
    if (t >= 448 && t < 448 + NCLS) NSs[t - 448] = nseeds[b * NCLS + (t - 448)];
    __syncthreads();

    size_t bn = (size_t)b * N + n;
    float x = sx[bn], y = sy[bn], z = sz[bn];

    const float kinv = 22.2222222f;   // 1/0.045
    float ps = 0.f;
#pragma unroll
    for (int c = wv; c < NCLS; c += 8) {
        int ns = NSs[c];
        float gdv = 0.f;
        if (ns > 0) {
            float pv = probs[((size_t)b * NCLS + c) * N + n];
            if (pv > PTHRESH) {
                float wbuf[SMAX];
                float sw = 0.f;
#pragma unroll
                for (int s = 0; s < SMAX; ++s) {
                    wbuf[s] = 0.f;
                    if (s < ns) {
                        const float* sd = &S[(c * SMAX + s) * 3];
                        float d2 = d2f(x, y, z, sd[0], sd[1], sd[2]);
                        wbuf[s] = __expf(-d2 * kinv);
                        sw += wbuf[s];
                    }
                }
                gdv = __fdividef(pv, sw + 1e-8f);
#pragma unroll
                for (int s = 0; s < SMAX; ++s)
                    if (s < ns) ps += __expf(10.f * wbuf[s] * gdv);
            } else {
                ps += (float)ns;   // exp(0)=1 per valid seed, exact
            }
        }
        gdS[c][lane] = gdv;
    }
    psum[wv][lane] = ps;
    __syncthreads();

    float tot = 0.f;
#pragma unroll
    for (int w = 0; w < 8; ++w) tot += psum[w][lane];
    float inv = __fdividef(1.f, tot);

    float* ob = out + (size_t)b * (NCLS * SMAX) * N + n;
#pragma unroll
    for (int k = 0; k < NCLS * SMAX; k += 8) {
        int kk = k + wv;
        if (kk >= NCLS * SMAX) break;
        int c = kk / SMAX, s = kk - c * SMAX;
        float o = 0.f;
        if (s < NSs[c]) {
            float gdv = gdS[c][lane];
            if (gdv > 0.f) {
                const float* sd = &S[(c * SMAX + s) * 3];
                float d2 = d2f(x, y, z, sd[0], sd[1], sd[2]);
                float wval = __expf(-d2 * kinv);
                o = __expf(10.f * wval * gdv) * inv;
            } else {
                o = inv;
            }
        }
        ob[(size_t)kk * N] = o;
    }
}

extern "C" void kernel_launch(void* const* d_in, const int* in_sizes, int n_in,
                              void* d_out, int out_size, void* d_ws, size_t ws_size,
                              hipStream_t stream) {
    const float* logits = (const float*)d_in[0];
    const float* pts    = (const float*)d_in[1];
    const float* offs   = (const float*)d_in[2];
    float* out = (float*)d_out;

    const int B = BB;
    const int BN = in_sizes[0] / NCLS;   // B*N
    const int N = BN / B;                // 65536

    // Workspace layout
    char* w = (char*)d_ws;
    size_t off = 0;
    auto take = [&](size_t bytes) -> void* {
        void* p = w + off;
        off = (off + bytes + 255) & ~(size_t)255;
        return p;
    };
    float* probs   = (float*)take((size_t)B * NCLS * N * sizeof(float));
    float* sx      = (float*)take((size_t)B * N * sizeof(float));
    float* sy      = (float*)take((size_t)B * N * sizeof(float));
    float* sz      = (float*)take((size_t)B * N * sizeof(float));
    float* seedxyz = (float*)take((size_t)B * NCLS * SMAX * 3 * sizeof(float));
    unsigned int* pcnt = (unsigned int*)take((size_t)B * NCLS * GABLK * sizeof(unsigned int));
    unsigned int* pfst = (unsigned int*)take((size_t)B * NCLS * GABLK * sizeof(unsigned int));
    int* nseeds        = (int*)take(B * NCLS * sizeof(int));
    unsigned long long* slots =
        (unsigned long long*)take((size_t)B * NCLS * SMAX * NSLOT * sizeof(unsigned long long));

    dim3 gA((N + 255) / 256, B);   // == (GABLK, B)
    k_setup<<<gA, 256, 0, stream>>>(logits, pts, offs, probs, sx, sy, sz,
                                    pcnt, pfst, (unsigned int*)slots, N);

    dim3 gB(FPS_SEG, NCLS, B);
    k_fps<<<gB, FPS_T, 0, stream>>>(probs, sx, sy, sz, pcnt, pfst, nseeds, seedxyz,
                                    slots, N);

    dim3 gC(N / 64, B);
    k_out<<<gC, 512, 0, stream>>>(probs, sx, sy, sz, nseeds, seedxyz, out, N);
}

// Round 6
// 81.121 us; speedup vs baseline: 1.2609x; 1.2609x over previous
//
#include <hip/hip_runtime.h>
#include <cstdint>

#define NCLS 13
#define SMAX 10
#define PTHRESH 0.05f
#define FPS_SEG 8        // blocks per (b,c)
#define FPS_T 512        // threads per FPS block (8 waves)
#define FPS_PPT 16       // points per thread: 8*512*16 = 65536
#define NSLOT 64         // publisher waves per (b,c) = FPS_SEG * FPS_T/64
#define GABLK 256        // k_setup blocks per batch (N/256)
#define BB 2             // batch
#define SLOT_DWORDS (BB * NCLS * SMAX * NSLOT * 2)

// Exact (un-fused) squared distance, matching numpy's ((dx*dx + dy*dy) + dz*dz) in f32.
__device__ __forceinline__ float d2f(float ax, float ay, float az,
                                     float bx, float by, float bz) {
    float dx = ax - bx;
    float dy = ay - by;
    float dz = az - bz;
    return __fadd_rn(__fadd_rn(__fmul_rn(dx, dx), __fmul_rn(dy, dy)), __fmul_rn(dz, dz));
}

// Monotone mapping float -> uint32. Never 0 for non-NaN input => key==0 means "empty".
__device__ __forceinline__ unsigned int fmono(float f) {
    unsigned int u = __float_as_uint(f);
    return (u & 0x80000000u) ? ~u : (u | 0x80000000u);
}

// Kernel A: class softmax, shifted coords (SoA), PER-BLOCK partial counts/first-index
// (full overwrite -> no zero-init, no global atomics), plus zeroing the FPS slots.
__global__ void k_setup(const float* __restrict__ logits, const float* __restrict__ pts,
                        const float* __restrict__ offs, float* __restrict__ probs,
                        float* __restrict__ sx, float* __restrict__ sy, float* __restrict__ sz,
                        unsigned int* __restrict__ pcnt, unsigned int* __restrict__ pfst,
                        unsigned int* __restrict__ slots32, int N) {
    int b = blockIdx.y;
    int n = blockIdx.x * blockDim.x + threadIdx.x;
    int t = threadIdx.x;
    __shared__ unsigned int sC[NCLS], sF[NCLS];
    if (t < NCLS) { sC[t] = 0u; sF[t] = 0xFFFFFFFFu; }
    __syncthreads();

    // zero FPS slots (every call: graph replays leave stale nonzero keys behind)
    if (b == 0) {
        for (unsigned int i = blockIdx.x * blockDim.x + t; i < SLOT_DWORDS;
             i += GABLK * 256)
            slots32[i] = 0u;
    }

    if (n < N) {
        size_t bn = (size_t)b * N + n;
        const float* L = logits + bn * NCLS;
        float v[NCLS];
        float mx = -INFINITY;
#pragma unroll
        for (int c = 0; c < NCLS; ++c) { v[c] = L[c]; mx = fmaxf(mx, v[c]); }
        float s = 0.f;
#pragma unroll
        for (int c = 0; c < NCLS; ++c) { v[c] = expf(v[c] - mx); s += v[c]; }
        int lane = t & 63;
        int wave_base = n - lane;
#pragma unroll
        for (int c = 0; c < NCLS; ++c) {
            float p = v[c] / s;
            probs[((size_t)b * NCLS + c) * N + n] = p;
            unsigned long long m = __ballot(p > PTHRESH);
            if (lane == 0 && m) {
                atomicAdd(&sC[c], (unsigned int)__popcll(m));
                atomicMin(&sF[c], (unsigned int)(wave_base + __ffsll(m) - 1));
            }
        }
        float x = pts[bn * 3 + 0] + offs[bn * 3 + 0];
        float y = pts[bn * 3 + 1] + offs[bn * 3 + 1];
        float z = pts[bn * 3 + 2] + offs[bn * 3 + 2];
        sx[bn] = x; sy[bn] = y; sz[bn] = z;
    }
    __syncthreads();
    if (t < NCLS) {
        pcnt[(b * NCLS + t) * GABLK + blockIdx.x] = sC[t];
        pfst[(b * NCLS + t) * GABLK + blockIdx.x] = sF[t];
    }
}

// Kernel B: deterministic FPS, wave-autonomous. 8 blocks x 8 waves per (b,c) = 64
// publisher waves; slots per (bc,step) = 64 u64 (one per lane of the polling wave).
// Per step: thread partial argmax -> 64-lane butterfly -> lane0 relaxed-store own slot
// -> every lane relaxed-polls its slot (no buffer_inv) -> butterfly max = winner.
// No __syncthreads, no LDS, no fences: the u64 key is pure value communication.
// __launch_bounds__(FPS_T, 1): min 1 wave/EU -> full VGPR budget -> the 64-float
// per-thread state (X,Y,Z,m) stays in registers (rounds 4/5 spilled at default budget).
__global__ __launch_bounds__(FPS_T, 1) void k_fps(
    const float* __restrict__ probs,
    const float* __restrict__ sx, const float* __restrict__ sy, const float* __restrict__ sz,
    const unsigned int* __restrict__ pcnt, const unsigned int* __restrict__ pfst,
    int* __restrict__ nseeds, float* __restrict__ seedxyz,
    unsigned long long* __restrict__ slots, int N) {
    int g = blockIdx.x;
    int c = blockIdx.y;
    int b = blockIdx.z;
    int bc = b * NCLS + c;
    int t = threadIdx.x, lane = t & 63, w = t >> 6;

    // Reduce per-block partials (each wave redundantly; identical ops -> identical result)
    const unsigned int* pc = pcnt + (size_t)bc * GABLK;
    const unsigned int* pf = pfst + (size_t)bc * GABLK;
    uint4 c4 = *(const uint4*)(pc + lane * 4);
    uint4 f4 = *(const uint4*)(pf + lane * 4);
    unsigned int cnt = c4.x + c4.y + c4.z + c4.w;
    unsigned int fst = min(min(f4.x, f4.y), min(f4.z, f4.w));
#pragma unroll
    for (int off = 1; off < 64; off <<= 1) {
        cnt += __shfl_xor(cnt, off, 64);
        fst = min(fst, __shfl_xor(fst, off, 64));
    }
    int ns = min(SMAX, min((int)cnt / 50, (int)cnt));
    if (g == 0 && t == 0) nseeds[bc] = ns;
    if (ns == 0) return;

    const float* px = sx + (size_t)b * N;
    const float* py = sy + (size_t)b * N;
    const float* pz = sz + (size_t)b * N;
    const float* pp = probs + (size_t)bc * N;

    int base = g * (FPS_T * FPS_PPT) + t;
    float X[FPS_PPT], Y[FPS_PPT], Z[FPS_PPT], m[FPS_PPT];
    unsigned int vm = 0;
#pragma unroll
    for (int j = 0; j < FPS_PPT; ++j) {
        int n = base + (j << 9);
        X[j] = px[n]; Y[j] = py[n]; Z[j] = pz[n];
        if (pp[n] > PTHRESH) vm |= (1u << j);
        m[j] = INFINITY;
    }

    int st = (int)fst;
    float cx = px[st], cy = py[st], cz = pz[st];
    if (g == 0 && t == 0) {
        float* sd = seedxyz + (size_t)bc * SMAX * 3;
        sd[0] = cx; sd[1] = cy; sd[2] = cz;
    }

    for (int s = 1; s < ns; ++s) {
        float best = -INFINITY;
        int bidx = 0;
#pragma unroll
        for (int j = 0; j < FPS_PPT; ++j) {   // ascending n => first-occurrence tiebreak
            int n = base + (j << 9);
            float d2 = d2f(X[j], Y[j], Z[j], cx, cy, cz);
            float add = ((vm >> j) & 1u) ? 0.0f : -INFINITY;
            float nm = fminf(m[j], __fadd_rn(d2, add));
            m[j] = nm;
            if (nm > best) { best = nm; bidx = n; }
        }
        unsigned long long key =
            ((unsigned long long)fmono(best) << 32) | (unsigned int)(~(unsigned int)bidx);
#pragma unroll
        for (int off = 1; off < 64; off <<= 1) {
            unsigned long long ok = __shfl_xor(key, off, 64);
            if (ok > key) key = ok;
        }
        unsigned long long* sl = slots + ((size_t)bc * SMAX + s) * NSLOT;
        if (lane == 0)
            __hip_atomic_store(&sl[g * (FPS_T / 64) + w], key,
                               __ATOMIC_RELAXED, __HIP_MEMORY_SCOPE_AGENT);
        asm volatile("" ::: "memory");   // pin publish before poll (no runtime cost)
        unsigned long long k = 0ULL;
        while (true) {
            if (k == 0ULL)
                k = __hip_atomic_load(&sl[lane], __ATOMIC_RELAXED, __HIP_MEMORY_SCOPE_AGENT);
            if (__all(k != 0ULL)) break;
        }
        asm volatile("" ::: "memory");
#pragma unroll
        for (int off = 1; off < 64; off <<= 1) {
            unsigned long long ok = __shfl_xor(k, off, 64);
            if (ok > k) k = ok;
        }
        int widx = (int)(~(unsigned int)k);
        cx = px[widx]; cy = py[widx]; cz = pz[widx];
        if (g == 0 && t == 0) {
            float* sd = seedxyz + ((size_t)bc * SMAX + s) * 3;
            sd[0] = cx; sd[1] = cy; sd[2] = cz;
        }
    }
}

// Kernel C: 512-thread block owns 64 points. Wave w (lane=point) handles classes
// {w, w+8} in pass 1 (gd + partial sumexp -> LDS), rows k==w (mod 8) in pass 2.
__global__ __launch_bounds__(512) void k_out(
    const float* __restrict__ probs,
    const float* __restrict__ sx, const float* __restrict__ sy,
    const float* __restrict__ sz,
    const int* __restrict__ nseeds, const float* __restrict__ seedxyz,
    float* __restrict__ out, int N) {
    int b = blockIdx.y;
    int t = threadIdx.x;
    int lane = t & 63;       // point within 64-point tile
    int wv = t >> 6;         // wave 0..7
    int n = blockIdx.x * 64 + lane;

    __shared__ float S[NCLS * SMAX * 3];
    __shared__ int NSs[NCLS];
    __shared__ float gdS[NCLS][64];
    __shared__ float psum[8][64];
    if (t < NCLS * SMAX * 3) S[t] = seedxyz[(size_t)b * NCLS * SMAX * 3 + t];
    if (t >= 448 && t < 448 + NCLS) NSs[t - 448] = nseeds[b * NCLS + (t - 448)];
    __syncthreads();

    size_t bn = (size_t)b * N + n;
    float x = sx[bn], y = sy[bn], z = sz[bn];

    const float kinv = 22.2222222f;   // 1/0.045
    float ps = 0.f;
#pragma unroll
    for (int c = wv; c < NCLS; c += 8) {
        int ns = NSs[c];
        float gdv = 0.f;
        if (ns > 0) {
            float pv = probs[((size_t)b * NCLS + c) * N + n];
            if (pv > PTHRESH) {
                float wbuf[SMAX];
                float sw = 0.f;
#pragma unroll
                for (int s = 0; s < SMAX; ++s) {
                    wbuf[s] = 0.f;
                    if (s < ns) {
                        const float* sd = &S[(c * SMAX + s) * 3];
                        float d2 = d2f(x, y, z, sd[0], sd[1], sd[2]);
                        wbuf[s] = __expf(-d2 * kinv);
                        sw += wbuf[s];
                    }
                }
                gdv = __fdividef(pv, sw + 1e-8f);
#pragma unroll
                for (int s = 0; s < SMAX; ++s)
                    if (s < ns) ps += __expf(10.f * wbuf[s] * gdv);
            } else {
                ps += (float)ns;   // exp(0)=1 per valid seed, exact
            }
        }
        gdS[c][lane] = gdv;
    }
    psum[wv][lane] = ps;
    __syncthreads();

    float tot = 0.f;
#pragma unroll
    for (int w = 0; w < 8; ++w) tot += psum[w][lane];
    float inv = __fdividef(1.f, tot);

    float* ob = out + (size_t)b * (NCLS * SMAX) * N + n;
#pragma unroll
    for (int k = 0; k < NCLS * SMAX; k += 8) {
        int kk = k + wv;
        if (kk >= NCLS * SMAX) break;
        int c = kk / SMAX, s = kk - c * SMAX;
        float o = 0.f;
        if (s < NSs[c]) {
            float gdv = gdS[c][lane];
            if (gdv > 0.f) {
                const float* sd = &S[(c * SMAX + s) * 3];
                float d2 = d2f(x, y, z, sd[0], sd[1], sd[2]);
                float wval = __expf(-d2 * kinv);
                o = __expf(10.f * wval * gdv) * inv;
            } else {
                o = inv;
            }
        }
        ob[(size_t)kk * N] = o;
    }
}

extern "C" void kernel_launch(void* const* d_in, const int* in_sizes, int n_in,
                              void* d_out, int out_size, void* d_ws, size_t ws_size,
                              hipStream_t stream) {
    const float* logits = (const float*)d_in[0];
    const float* pts    = (const float*)d_in[1];
    const float* offs   = (const float*)d_in[2];
    float* out = (float*)d_out;

    const int B = BB;
    const int BN = in_sizes[0] / NCLS;   // B*N
    const int N = BN / B;                // 65536

    // Workspace layout
    char* w = (char*)d_ws;
    size_t off = 0;
    auto take = [&](size_t bytes) -> void* {
        void* p = w + off;
        off = (off + bytes + 255) & ~(size_t)255;
        return p;
    };
    float* probs   = (float*)take((size_t)B * NCLS * N * sizeof(float));
    float* sx      = (float*)take((size_t)B * N * sizeof(float));
    float* sy      = (float*)take((size_t)B * N * sizeof(float));
    float* sz      = (float*)take((size_t)B * N * sizeof(float));
    float* seedxyz = (float*)take((size_t)B * NCLS * SMAX * 3 * sizeof(float));
    unsigned int* pcnt = (unsigned int*)take((size_t)B * NCLS * GABLK * sizeof(unsigned int));
    unsigned int* pfst = (unsigned int*)take((size_t)B * NCLS * GABLK * sizeof(unsigned int));
    int* nseeds        = (int*)take(B * NCLS * sizeof(int));
    unsigned long long* slots =
        (unsigned long long*)take((size_t)B * NCLS * SMAX * NSLOT * sizeof(unsigned long long));

    dim3 gA((N + 255) / 256, B);   // == (GABLK, B)
    k_setup<<<gA, 256, 0, stream>>>(logits, pts, offs, probs, sx, sy, sz,
                                    pcnt, pfst, (unsigned int*)slots, N);

    dim3 gB(FPS_SEG, NCLS, B);
    k_fps<<<gB, FPS_T, 0, stream>>>(probs, sx, sy, sz, pcnt, pfst, nseeds, seedxyz,
                                    slots, N);

    dim3 gC(N / 64, B);
    k_out<<<gC, 512, 0, stream>>>(probs, sx, sy, sz, nseeds, seedxyz, out, N);
}